// Round 1
// baseline (2206.875 us; speedup 1.0000x reference)
//
#include <hip/hip_runtime.h>

#define D_ 256
#define T_ 2048
#define K_ 1024
#define L_ 8
#define B_ 16
#define BM_ 64
#define RS_ 260   // padded LDS row stride (floats): 16B-aligned, bank-shift 4

// ---------------------------------------------------------------------------
// Prep: ww[l*K + c] = sum_d codebooks[l][c][d]^2   (one wave per row)
// ---------------------------------------------------------------------------
__global__ __launch_bounds__(256, 4)
void rvq_ww_kernel(const float* __restrict__ cb, float* __restrict__ ww) {
    const int row  = blockIdx.x * 4 + (threadIdx.x >> 6);
    const int lane = threadIdx.x & 63;
    const float4 v = *reinterpret_cast<const float4*>(cb + (size_t)row * D_ + (lane << 2));
    float s = v.x * v.x + v.y * v.y + v.z * v.z + v.w * v.w;
    #pragma unroll
    for (int off = 1; off < 64; off <<= 1) s += __shfl_xor(s, off, 64);
    if (lane == 0) ww[row] = s;
}

// ---------------------------------------------------------------------------
// Main: block = 256 threads (4 waves), 64 tokens. Wave owns 16 tokens.
// Residual tile f32 in LDS. Codebook streamed via registers (L1/L2-hot).
// Scores: (rr - 2*dot) + ww, argmin with numpy first-min tie-break.
// output = x - r_final; indices written as float.
// ---------------------------------------------------------------------------
__global__ __launch_bounds__(256, 2)
void rvq_main_kernel(const float* __restrict__ x, const float* __restrict__ cb,
                     const float* __restrict__ ww, float* __restrict__ out) {
    __shared__ float r_lds[BM_ * RS_];
    const int tid  = threadIdx.x;
    const int lane = tid & 63;
    const int wv   = tid >> 6;
    const int tok0 = blockIdx.x * BM_;
    const int b    = tok0 >> 11;          // / T_
    const int tb   = tok0 & (T_ - 1);

    // stage x (B,D,T) -> r_lds[t][d], coalesced over t
    for (int i = tid; i < BM_ * D_; i += 256) {
        const int d = i >> 6, t = i & 63;
        r_lds[t * RS_ + d] = x[((size_t)b * D_ + d) * T_ + tb + t];
    }
    __syncthreads();

    const int tw0 = wv * 16;

    #pragma unroll 1
    for (int l = 0; l < L_; ++l) {
        const float* __restrict__ cbl = cb + (size_t)l * K_ * D_;
        const float* __restrict__ wwl = ww + l * K_;

        // rr[t] = ||r_t||^2  (wave-parallel + shuffle tree)
        float rr[16];
        unsigned long long best[16];
        #pragma unroll
        for (int tt = 0; tt < 16; ++tt) {
            const float4 v = *reinterpret_cast<const float4*>(
                r_lds + (tw0 + tt) * RS_ + (lane << 2));
            float s = v.x * v.x + v.y * v.y + v.z * v.z + v.w * v.w;
            #pragma unroll
            for (int off = 1; off < 64; off <<= 1) s += __shfl_xor(s, off, 64);
            rr[tt] = s;
            best[tt] = ~0ull;
        }

        // distance GEMM: cands c = o*256 + sub*64 + lane
        #pragma unroll 1
        for (int o = 0; o < 4; ++o) {
            float acc[4][16];
            #pragma unroll
            for (int sub = 0; sub < 4; ++sub) {
                #pragma unroll
                for (int tt = 0; tt < 16; ++tt) acc[sub][tt] = 0.0f;
            }

            #pragma unroll 1
            for (int dc = 0; dc < D_; dc += 8) {
                float w_[4][8];
                #pragma unroll
                for (int sub = 0; sub < 4; ++sub) {
                    const float* wp = cbl + (size_t)((o << 8) + (sub << 6) + lane) * D_ + dc;
                    const float4 a  = *reinterpret_cast<const float4*>(wp);
                    const float4 bq = *reinterpret_cast<const float4*>(wp + 4);
                    w_[sub][0] = a.x;  w_[sub][1] = a.y;  w_[sub][2] = a.z;  w_[sub][3] = a.w;
                    w_[sub][4] = bq.x; w_[sub][5] = bq.y; w_[sub][6] = bq.z; w_[sub][7] = bq.w;
                }
                #pragma unroll
                for (int tt = 0; tt < 16; ++tt) {
                    const float* rp = r_lds + (tw0 + tt) * RS_ + dc;  // wave-uniform broadcast
                    const float4 ra = *reinterpret_cast<const float4*>(rp);
                    const float4 rb = *reinterpret_cast<const float4*>(rp + 4);
                    #pragma unroll
                    for (int sub = 0; sub < 4; ++sub) {
                        float a0 = acc[sub][tt];
                        a0 = fmaf(w_[sub][0], ra.x, a0);
                        a0 = fmaf(w_[sub][1], ra.y, a0);
                        a0 = fmaf(w_[sub][2], ra.z, a0);
                        a0 = fmaf(w_[sub][3], ra.w, a0);
                        a0 = fmaf(w_[sub][4], rb.x, a0);
                        a0 = fmaf(w_[sub][5], rb.y, a0);
                        a0 = fmaf(w_[sub][6], rb.z, a0);
                        a0 = fmaf(w_[sub][7], rb.w, a0);
                        acc[sub][tt] = a0;
                    }
                }
            }

            #pragma unroll
            for (int sub = 0; sub < 4; ++sub) {
                const int c = (o << 8) + (sub << 6) + lane;
                const float wwc = wwl[c];
                #pragma unroll
                for (int tt = 0; tt < 16; ++tt) {
                    // match reference: (rr - 2*dots) + ww, separate roundings
                    const float sc = __fadd_rn(
                        __fsub_rn(rr[tt], __fmul_rn(2.0f, acc[sub][tt])), wwc);
                    const unsigned fb = __float_as_uint(sc);
                    const unsigned ob = fb ^ ((unsigned)((int)fb >> 31) | 0x80000000u);
                    const unsigned long long key =
                        (((unsigned long long)ob) << 32) | (unsigned)c;
                    if (key < best[tt]) best[tt] = key;
                }
            }
        }

        // cross-lane argmin (ties -> smaller c, matching numpy first-min)
        #pragma unroll
        for (int tt = 0; tt < 16; ++tt) {
            unsigned long long v = best[tt];
            #pragma unroll
            for (int off = 1; off < 64; off <<= 1) {
                const unsigned long long o2 = __shfl_xor(v, off, 64);
                if (o2 < v) v = o2;
            }
            best[tt] = v;
        }

        // indices (B,L,T) as float, after the quantized block
        #pragma unroll
        for (int tt = 0; tt < 16; ++tt) {
            if (lane == tt) {
                const unsigned idx = (unsigned)(best[tt] & 0xffffffffull);
                out[(size_t)B_ * D_ * T_ + ((size_t)b * L_ + l) * T_ + tb + tw0 + tt] =
                    (float)idx;
            }
        }

        // residual update: r -= codebook[idx]  (exact f32, coalesced gather)
        #pragma unroll 1
        for (int tt = 0; tt < 16; ++tt) {
            const unsigned idx = (unsigned)(best[tt] & 0xffffffffull) & (K_ - 1);
            const float4 wq = *reinterpret_cast<const float4*>(
                cbl + (size_t)idx * D_ + (lane << 2));
            float* rp = r_lds + (tw0 + tt) * RS_ + (lane << 2);
            float4 rv = *reinterpret_cast<float4*>(rp);
            rv.x = __fsub_rn(rv.x, wq.x);
            rv.y = __fsub_rn(rv.y, wq.y);
            rv.z = __fsub_rn(rv.z, wq.z);
            rv.w = __fsub_rn(rv.w, wq.w);
            *reinterpret_cast<float4*>(rp) = rv;
        }
        __syncthreads();
    }

    // epilogue: quantized = x - r_final
    for (int i = tid; i < BM_ * D_; i += 256) {
        const int d = i >> 6, t = i & 63;
        const size_t gi = ((size_t)b * D_ + d) * T_ + tb + t;
        out[gi] = __fsub_rn(x[gi], r_lds[t * RS_ + d]);
    }
}

extern "C" void kernel_launch(void* const* d_in, const int* in_sizes, int n_in,
                              void* d_out, int out_size, void* d_ws, size_t ws_size,
                              hipStream_t stream) {
    const float* x  = (const float*)d_in[0];
    const float* cb = (const float*)d_in[1];
    float* out = (float*)d_out;
    float* ww  = (float*)d_ws;   // 8192 floats = 32 KB

    hipLaunchKernelGGL(rvq_ww_kernel, dim3((L_ * K_) / 4), dim3(256), 0, stream, cb, ww);
    hipLaunchKernelGGL(rvq_main_kernel, dim3((B_ * T_) / BM_), dim3(256), 0, stream,
                       x, cb, ww, out);
}

// Round 2
// 1119.147 us; speedup vs baseline: 1.9719x; 1.9719x over previous
//
#include <hip/hip_runtime.h>

#define D_ 256
#define T_ 2048
#define K_ 1024
#define L_ 8
#define B_ 16
#define BM_ 32
#define RS_ 260   // padded f32 LDS row stride
#define THETA 0.5f
#define EXCAP 160
#define LCAP  416  // 256 wave-chunk minima + 160 extras = hard upper bound

typedef _Float16 f16x8 __attribute__((ext_vector_type(8)));
typedef float    f32x4 __attribute__((ext_vector_type(4)));

struct __align__(8) h4s { _Float16 x, y, z, w; };

__device__ __forceinline__ unsigned long long packkey(float sc, unsigned cand) {
    const unsigned fb = __float_as_uint(sc);
    const unsigned ob = fb ^ ((unsigned)((int)fb >> 31) | 0x80000000u);
    return (((unsigned long long)ob) << 32) | cand;
}
__device__ __forceinline__ float unpackf(unsigned long long key) {
    const unsigned ob = (unsigned)(key >> 32);
    const unsigned fb = (ob & 0x80000000u) ? (ob ^ 0x80000000u) : ~ob;
    return __uint_as_float(fb);
}

// ---------------------------------------------------------------------------
// Prep 1 (VERBATIM round 1): ww[l*K + c] = ||codebook[l][c]||^2
// ---------------------------------------------------------------------------
__global__ __launch_bounds__(256, 4)
void rvq_ww_kernel(const float* __restrict__ cb, float* __restrict__ ww) {
    const int row  = blockIdx.x * 4 + (threadIdx.x >> 6);
    const int lane = threadIdx.x & 63;
    const float4 v = *reinterpret_cast<const float4*>(cb + (size_t)row * D_ + (lane << 2));
    float s = v.x * v.x + v.y * v.y + v.z * v.z + v.w * v.w;
    #pragma unroll
    for (int off = 1; off < 64; off <<= 1) s += __shfl_xor(s, off, 64);
    if (lane == 0) ww[row] = s;
}

// ---------------------------------------------------------------------------
// Prep 2: codebooks f32 -> f16 into workspace
// ---------------------------------------------------------------------------
__global__ __launch_bounds__(256)
void rvq_cvt_kernel(const float* __restrict__ cb, _Float16* __restrict__ cb16) {
    const int i = (blockIdx.x * 256 + threadIdx.x) * 8;
    const float4 a = *reinterpret_cast<const float4*>(cb + i);
    const float4 b = *reinterpret_cast<const float4*>(cb + i + 4);
    f16x8 v;
    v[0] = (_Float16)a.x; v[1] = (_Float16)a.y; v[2] = (_Float16)a.z; v[3] = (_Float16)a.w;
    v[4] = (_Float16)b.x; v[5] = (_Float16)b.y; v[6] = (_Float16)b.z; v[7] = (_Float16)b.w;
    *reinterpret_cast<f16x8*>(cb16 + i) = v;
}

// ---------------------------------------------------------------------------
// Main: block = 256 threads (4 waves), 32 tokens.
// f16 MFMA distance screen + theta-window exact-f32 (round-1-identical) argmin.
// ---------------------------------------------------------------------------
__global__ __launch_bounds__(256)
void rvq_main_kernel(const float* __restrict__ x, const float* __restrict__ cbf,
                     const _Float16* __restrict__ cb16, const float* __restrict__ ww,
                     float* __restrict__ out) {
    __shared__ float               rf[BM_ * RS_];      // exact f32 residual
    __shared__ _Float16            rh[BM_ * D_];       // f16 mirror (XOR-swizzled)
    __shared__ unsigned long long  wkeys[8][BM_];      // per wave-chunk per-token min
    __shared__ unsigned long long  bmk[BM_];
    __shared__ unsigned long long  finalk[BM_];
    __shared__ float               rrs[BM_];
    __shared__ int                 idxs[BM_];
    __shared__ float               exsc[EXCAP];
    __shared__ unsigned            extc[EXCAP];
    __shared__ unsigned            list[LCAP];
    __shared__ int                 cnts[2];

    const int tid  = threadIdx.x;
    const int lane = tid & 63;
    const int wv   = tid >> 6;          // 0..3
    const int g    = lane >> 4;         // 0..3
    const int c4   = lane & 15;
    const int tok0 = blockIdx.x * BM_;
    const int b    = tok0 >> 11;
    const int tb   = tok0 & (T_ - 1);

    // stage x -> rf (f32) and rh (f16, swizzled)
    for (int i = tid; i < BM_ * D_; i += 256) {
        const int d = i >> 5, t = i & 31;
        const float v = x[((size_t)b * D_ + d) * T_ + tb + t];
        rf[t * RS_ + d] = v;
        rh[((unsigned)(t * 512 + d * 2) ^ ((t & 7) << 4)) >> 1] = (_Float16)v;
    }
    __syncthreads();

    #pragma unroll 1
    for (int l = 0; l < L_; ++l) {
        const float*    __restrict__ cbl  = cbf  + (size_t)l * K_ * D_;
        const _Float16* __restrict__ cbl6 = cb16 + (size_t)l * K_ * D_;
        const float*    __restrict__ wwl  = ww + l * K_;

        // rr (VERBATIM round-1 arithmetic) + per-layer inits
        #pragma unroll
        for (int tt = 0; tt < 8; ++tt) {
            const int t = wv * 8 + tt;
            const float4 v = *reinterpret_cast<const float4*>(rf + t * RS_ + (lane << 2));
            float s = v.x * v.x + v.y * v.y + v.z * v.z + v.w * v.w;
            #pragma unroll
            for (int off = 1; off < 64; off <<= 1) s += __shfl_xor(s, off, 64);
            if (lane == 0) rrs[t] = s;
        }
        if (tid < BM_) finalk[tid] = ~0ull;
        if (tid == 0) { cnts[0] = 0; cnts[1] = 0; }
        __syncthreads();

        // ---- f16 MFMA distance screen: 2 chunks of 128 cands per wave ----
        #pragma unroll 1
        for (int ch = 0; ch < 2; ++ch) {
            const int cbase = (wv * 2 + ch) * 128;
            f32x4 acc[2][8];
            #pragma unroll
            for (int m = 0; m < 2; ++m)
                #pragma unroll
                for (int n = 0; n < 8; ++n)
                    acc[m][n] = (f32x4){0.f, 0.f, 0.f, 0.f};

            #pragma unroll 2
            for (int k = 0; k < 8; ++k) {
                f16x8 af[2];
                #pragma unroll
                for (int m = 0; m < 2; ++m) {
                    const int t = m * 16 + c4;
                    const unsigned byte = (unsigned)(t * 512 + k * 64 + g * 16) ^ ((t & 7) << 4);
                    af[m] = *reinterpret_cast<const f16x8*>(
                        reinterpret_cast<const char*>(rh) + byte);
                }
                #pragma unroll
                for (int n = 0; n < 8; ++n) {
                    const int cand = cbase + n * 16 + c4;
                    const f16x8 bf = *reinterpret_cast<const f16x8*>(
                        cbl6 + (size_t)cand * D_ + k * 32 + g * 8);
                    #pragma unroll
                    for (int m = 0; m < 2; ++m)
                        acc[m][n] = __builtin_amdgcn_mfma_f32_16x16x32_f16(
                            af[m], bf, acc[m][n], 0, 0, 0);
                }
            }

            float wwv[8];
            #pragma unroll
            for (int n = 0; n < 8; ++n) wwv[n] = wwl[cbase + n * 16 + c4];

            // per-token (token = m*16 + g*4 + j) wave-chunk min
            unsigned long long kmin[2][4];
            #pragma unroll
            for (int m = 0; m < 2; ++m) {
                #pragma unroll
                for (int j = 0; j < 4; ++j) {
                    unsigned long long km = ~0ull;
                    #pragma unroll
                    for (int n = 0; n < 8; ++n) {
                        const float sc = fmaf(-2.f, acc[m][n][j], wwv[n]);
                        const unsigned long long key = packkey(sc, (unsigned)(cbase + n * 16 + c4));
                        if (key < km) km = key;
                    }
                    #pragma unroll
                    for (int off = 1; off < 16; off <<= 1) {
                        const unsigned long long o2 = __shfl_xor(km, off, 64);
                        if (o2 < km) km = o2;
                    }
                    kmin[m][j] = km;
                    if (c4 == 0) wkeys[wv * 2 + ch][m * 16 + g * 4 + j] = km;
                }
            }
            // extras: anything within THETA of the wave-chunk min (superset of block window)
            #pragma unroll
            for (int m = 0; m < 2; ++m)
                #pragma unroll
                for (int n = 0; n < 8; ++n)
                    #pragma unroll
                    for (int j = 0; j < 4; ++j) {
                        const float sc = fmaf(-2.f, acc[m][n][j], wwv[n]);
                        const unsigned cand = (unsigned)(cbase + n * 16 + c4);
                        const unsigned long long key = packkey(sc, cand);
                        if (key != kmin[m][j] && sc <= unpackf(kmin[m][j]) + THETA) {
                            const int p = atomicAdd(&cnts[0], 1);
                            if (p < EXCAP) {
                                exsc[p] = sc;
                                extc[p] = ((unsigned)(m * 16 + g * 4 + j) << 16) | cand;
                            }
                        }
                    }
        }
        __syncthreads();

        // block min per token
        if (tid < BM_) {
            unsigned long long mm = ~0ull;
            #pragma unroll
            for (int w8 = 0; w8 < 8; ++w8)
                if (wkeys[w8][tid] < mm) mm = wkeys[w8][tid];
            bmk[tid] = mm;
        }
        __syncthreads();

        // build exact-recompute list: window members vs BLOCK min
        const int ne = min(cnts[0], EXCAP);
        for (int i = tid; i < 256 + ne; i += 256) {
            float sc; unsigned tc; int t;
            if (i < 256) {
                const int w8 = i >> 5, t0 = i & 31;
                const unsigned long long k = wkeys[w8][t0];
                sc = unpackf(k); t = t0;
                tc = ((unsigned)t0 << 16) | (unsigned)(k & 0xffffffffull);
            } else {
                sc = exsc[i - 256]; tc = extc[i - 256]; t = (int)(tc >> 16);
            }
            if (sc <= unpackf(bmk[t]) + THETA) {
                const int p = atomicAdd(&cnts[1], 1);
                if (p < LCAP) list[p] = tc;
            }
        }
        __syncthreads();

        // exact f32 recompute (round-1-identical fmaf chain) + final argmin
        const int nl = min(cnts[1], LCAP);
        for (int e = tid; e < nl; e += 256) {
            const unsigned tc = list[e];
            const int t = (int)(tc >> 16), cd = (int)(tc & 0xffffu);
            float a0 = 0.0f;
            #pragma unroll 4
            for (int dc = 0; dc < D_; dc += 8) {
                const float4 ra = *reinterpret_cast<const float4*>(rf + t * RS_ + dc);
                const float4 rb = *reinterpret_cast<const float4*>(rf + t * RS_ + dc + 4);
                const float4 wa = *reinterpret_cast<const float4*>(cbl + (size_t)cd * D_ + dc);
                const float4 wb = *reinterpret_cast<const float4*>(cbl + (size_t)cd * D_ + dc + 4);
                a0 = fmaf(wa.x, ra.x, a0);
                a0 = fmaf(wa.y, ra.y, a0);
                a0 = fmaf(wa.z, ra.z, a0);
                a0 = fmaf(wa.w, ra.w, a0);
                a0 = fmaf(wb.x, rb.x, a0);
                a0 = fmaf(wb.y, rb.y, a0);
                a0 = fmaf(wb.z, rb.z, a0);
                a0 = fmaf(wb.w, rb.w, a0);
            }
            const float sc = __fadd_rn(__fsub_rn(rrs[t], __fmul_rn(2.0f, a0)), wwl[cd]);
            atomicMin(&finalk[t], packkey(sc, (unsigned)cd));
        }
        __syncthreads();

        if (tid < BM_) {
            const unsigned idx = (unsigned)(finalk[tid] & 0xffffffffull);
            idxs[tid] = (int)idx;
            out[(size_t)B_ * D_ * T_ + ((size_t)b * L_ + l) * T_ + tb + tid] = (float)idx;
        }
        __syncthreads();

        // residual update (exact f32, round-1 semantics) + f16 refresh
        for (int f4 = tid; f4 < BM_ * 64; f4 += 256) {
            const int t = f4 >> 6, s = f4 & 63;
            const int idx = idxs[t];
            const float4 wq = *reinterpret_cast<const float4*>(cbl + (size_t)idx * D_ + s * 4);
            float* rp = rf + t * RS_ + s * 4;
            float4 rv = *reinterpret_cast<float4*>(rp);
            rv.x = __fsub_rn(rv.x, wq.x);
            rv.y = __fsub_rn(rv.y, wq.y);
            rv.z = __fsub_rn(rv.z, wq.z);
            rv.w = __fsub_rn(rv.w, wq.w);
            *reinterpret_cast<float4*>(rp) = rv;
            const unsigned byte = (unsigned)(t * 512 + s * 8) ^ ((t & 7) << 4);
            h4s hv;
            hv.x = (_Float16)rv.x; hv.y = (_Float16)rv.y;
            hv.z = (_Float16)rv.z; hv.w = (_Float16)rv.w;
            *reinterpret_cast<h4s*>(reinterpret_cast<char*>(rh) + byte) = hv;
        }
        __syncthreads();
    }

    // epilogue (VERBATIM round-1 semantics): quantized = x - r_final
    for (int i = tid; i < BM_ * D_; i += 256) {
        const int d = i >> 5, t = i & 31;
        const size_t gi = ((size_t)b * D_ + d) * T_ + tb + t;
        out[gi] = __fsub_rn(x[gi], rf[t * RS_ + d]);
    }
}

extern "C" void kernel_launch(void* const* d_in, const int* in_sizes, int n_in,
                              void* d_out, int out_size, void* d_ws, size_t ws_size,
                              hipStream_t stream) {
    const float* x  = (const float*)d_in[0];
    const float* cb = (const float*)d_in[1];
    float* out = (float*)d_out;
    float*     ww   = (float*)d_ws;                              // 32 KB
    _Float16*  cb16 = (_Float16*)((char*)d_ws + 32768);          // 4 MB

    hipLaunchKernelGGL(rvq_ww_kernel,  dim3((L_ * K_) / 4), dim3(256), 0, stream, cb, ww);
    hipLaunchKernelGGL(rvq_cvt_kernel, dim3((L_ * K_ * D_) / 2048), dim3(256), 0, stream, cb, cb16);
    hipLaunchKernelGGL(rvq_main_kernel, dim3((B_ * T_) / BM_), dim3(256), 0, stream,
                       x, cb, cb16, ww, out);
}